// Round 1
// baseline (74.930 us; speedup 1.0000x reference)
//
#include <hip/hip_runtime.h>

// BitGatConv collapses algebraically:
//   coefs = softmax(scores, axis=1)  =>  sum_j coefs[i,j,c] == 1
//   vals[i,c] = sum_j coefs[i,j,c] * nhs[i,c] = nhs[i,c]
// so output == nodes_ft @ weight. One [1536x256]@[256x64] fp32 GEMM.

#define N_NODES 1536
#define IN_CH 256
#define HC 64

__global__ __launch_bounds__(256) void nhs_gemm(const float* __restrict__ A,
                                                const float* __restrict__ W,
                                                float* __restrict__ out) {
    // block = 4 rows x 64 cols
    const int col = threadIdx.x & 63;
    const int row = (blockIdx.x << 2) + (threadIdx.x >> 6);

    const float* a = A + row * IN_CH;   // row of nodes_ft (broadcast within 64 lanes)
    const float* w = W + col;           // column of weight (coalesced across lanes)

    float acc = 0.0f;
#pragma unroll 8
    for (int k = 0; k < IN_CH; ++k) {
        acc = fmaf(a[k], w[k * HC], acc);
    }
    out[row * HC + col] = acc;
}

extern "C" void kernel_launch(void* const* d_in, const int* in_sizes, int n_in,
                              void* d_out, int out_size, void* d_ws, size_t ws_size,
                              hipStream_t stream) {
    // setup_inputs order: nodes_ft, adj_bias_mat, weight, conv_weight1, conv_weight2
    const float* nodes_ft = (const float*)d_in[0];
    const float* weight   = (const float*)d_in[2];
    float* out = (float*)d_out;

    nhs_gemm<<<N_NODES / 4, 256, 0, stream>>>(nodes_ft, weight, out);
}

// Round 2
// 73.862 us; speedup vs baseline: 1.0145x; 1.0145x over previous
//
#include <hip/hip_runtime.h>

// BitGatConv collapses algebraically:
//   coefs = softmax(scores, axis=1)  =>  sum_j coefs[i,j,c] == 1
//   vals[i,c] = sum_j coefs[i,j,c] * nhs[i,c] = nhs[i,c]
// so output == nodes_ft @ weight. One [1536x256]@[256x64] fp32 GEMM.
//
// Mapping: thread = (1 row, 4 consecutive cols) so both W and A are read as
// float4 (4x fewer VMEM instructions than scalar per-k loads). Block = 128
// threads = 8 rows x 16 col-quads; grid = 192 blocks -> 192 CUs x 2 waves.
// Per k, a wave's 64 lanes (4 rows x 16 cq) request 256 contiguous bytes of
// W (coalesced, rows broadcast) -- L1/L2 resident across blocks.

#define N_NODES 1536
#define IN_CH 256
#define HC 64

__global__ __launch_bounds__(128) void nhs_gemm(const float* __restrict__ A,
                                                const float* __restrict__ W,
                                                float* __restrict__ out) {
    const int cq  = threadIdx.x & 15;                       // col-quad 0..15
    const int row = (blockIdx.x << 3) + (threadIdx.x >> 4); // 8 rows/block

    const float* a = A + row * IN_CH;
    const float* w = W + (cq << 2);

    float4 acc = make_float4(0.f, 0.f, 0.f, 0.f);
#pragma unroll 4
    for (int k = 0; k < IN_CH; k += 4) {
        const float4 av = *(const float4*)(a + k);
        const float4 w0 = *(const float4*)(w + (k + 0) * HC);
        const float4 w1 = *(const float4*)(w + (k + 1) * HC);
        const float4 w2 = *(const float4*)(w + (k + 2) * HC);
        const float4 w3 = *(const float4*)(w + (k + 3) * HC);
        acc.x = fmaf(av.w, w3.x, fmaf(av.z, w2.x, fmaf(av.y, w1.x, fmaf(av.x, w0.x, acc.x))));
        acc.y = fmaf(av.w, w3.y, fmaf(av.z, w2.y, fmaf(av.y, w1.y, fmaf(av.x, w0.y, acc.y))));
        acc.z = fmaf(av.w, w3.z, fmaf(av.z, w2.z, fmaf(av.y, w1.z, fmaf(av.x, w0.z, acc.z))));
        acc.w = fmaf(av.w, w3.w, fmaf(av.z, w2.w, fmaf(av.y, w1.w, fmaf(av.x, w0.w, acc.w))));
    }
    *(float4*)(out + row * HC + (cq << 2)) = acc;
}

extern "C" void kernel_launch(void* const* d_in, const int* in_sizes, int n_in,
                              void* d_out, int out_size, void* d_ws, size_t ws_size,
                              hipStream_t stream) {
    // setup_inputs order: nodes_ft, adj_bias_mat, weight, conv_weight1, conv_weight2
    const float* nodes_ft = (const float*)d_in[0];
    const float* weight   = (const float*)d_in[2];
    float* out = (float*)d_out;

    nhs_gemm<<<N_NODES / 8, 128, 0, stream>>>(nodes_ft, weight, out);
}